// Round 10
// baseline (1281.105 us; speedup 1.0000x reference)
//
#include <hip/hip_runtime.h>
#include <hip/hip_bf16.h>
#include <math.h>

#define BB 64
#define TT 128
#define T1 127
#define NNODE 2000
#define EE 300
#define HID 256
#define NHEADS 5
#define DD 16
#define G3 768
#define ATT 1280

typedef _Float16 h2_t __attribute__((ext_vector_type(2)));
typedef short short8 __attribute__((ext_vector_type(8)));
typedef float f32x4 __attribute__((ext_vector_type(4)));

__device__ __forceinline__ float dot2(h2_t a, h2_t b, float c) {
    asm("v_dot2_f32_f16 %0, %1, %2, %0" : "+v"(c) : "v"(a), "v"(b));
    return c;
}

__device__ __forceinline__ unsigned short f2bf(float f) {
    unsigned u = __float_as_uint(f);
    unsigned r = (u + 0x7FFFu + ((u >> 16) & 1u)) >> 16;   // RNE
    return (unsigned short)r;
}

// ---------------- transpose + f32->bf16 ----------------
__global__ void k_tcvt(const float* __restrict__ src, unsigned short* __restrict__ dst, int R, int C) {
    int idx = blockIdx.x * 256 + threadIdx.x;
    if (idx < R * C) {
        int r = idx / C, c = idx % C;
        dst[c * R + r] = f2bf(src[idx]);
    }
}

// ---------------- f32 -> f16 convert ----------------
__global__ void k_cvt(const float* __restrict__ src, _Float16* __restrict__ dst, int n) {
    int i = blockIdx.x * 256 + threadIdx.x;
    if (i < n) dst[i] = (_Float16)src[i];
}

// ---------------- bf16 MFMA GEMM (R6-proven) ----------------
__global__ __launch_bounds__(256) void k_mgemm(
    const float* __restrict__ A, const unsigned short* __restrict__ B16,
    float* __restrict__ out, const float* __restrict__ bias,
    const int* __restrict__ trace, const int* __restrict__ na,
    int mode, int M, int K, int N, int strideA, int ntiles, int brow0, int Bld, int dotanh)
{
    __shared__ short As[64][40];
    __shared__ short Bt[64][40];
    __shared__ int baseLds[64];
    __shared__ int validLds[64];
    int tid = threadIdx.x;
    int bm = blockIdx.x / ntiles, bn = blockIdx.x % ntiles;
    int m0 = bm * 64, n0 = bn * 64;
    if (tid < 64) {
        int m = m0 + tid;
        int valid = (m < M) ? 1 : 0;
        int base = 0;
        if (valid) {
            if (mode == 2) {
                int i = m >> 6, bb = m & 63;
                int node = trace[bb * TT + i];
                int asg = (node < NNODE) ? na[bb * NNODE + node] : 0;
                base = (node * DD + asg) * EE;
            } else {
                base = m * strideA;
            }
        }
        baseLds[tid] = base;
        validLds[tid] = valid;
    }
    __syncthreads();

    int wv = tid >> 6, l = tid & 63;
    int lr = l & 15, lg = l >> 4;
    f32x4 acc[4];
#pragma unroll
    for (int cb = 0; cb < 4; cb++) acc[cb] = (f32x4){0.f, 0.f, 0.f, 0.f};

    int ar = tid >> 2, aq = tid & 3;
    int bk = tid >> 3, bq = tid & 7;
    int nsteps = (K + 31) >> 5;
    for (int it = 0; it < nsteps; it++) {
        int kk = it * 32;
        {
            int base = baseLds[ar], val = validLds[ar];
            short8 t1;
#pragma unroll
            for (int j = 0; j < 8; j++) {
                int kx = kk + aq * 8 + j;
                float v = (val && kx < K) ? A[(size_t)base + kx] : 0.f;
                t1[j] = (short)f2bf(v);
            }
            *(short8*)&As[ar][aq * 8] = t1;
        }
        {
            int kx = kk + bk;
            short8 t2;
            if (kx < K) {
                t2 = *(const short8*)(B16 + (size_t)(brow0 + kx) * Bld + n0 + bq * 8);
            } else {
#pragma unroll
                for (int j = 0; j < 8; j++) t2[j] = 0;
            }
#pragma unroll
            for (int j = 0; j < 8; j++) Bt[bq * 8 + j][bk] = t2[j];
        }
        __syncthreads();
        short8 a = *(const short8*)&As[wv * 16 + lr][lg * 8];
#pragma unroll
        for (int cb = 0; cb < 4; cb++) {
            short8 bfr = *(const short8*)&Bt[cb * 16 + lr][lg * 8];
            acc[cb] = __builtin_amdgcn_mfma_f32_16x16x32_bf16(a, bfr, acc[cb], 0, 0, 0);
        }
        __syncthreads();
    }
#pragma unroll
    for (int cb = 0; cb < 4; cb++) {
        int col = n0 + cb * 16 + lr;
#pragma unroll
        for (int q = 0; q < 4; q++) {
            int row = m0 + wv * 16 + lg * 4 + q;
            if (row < M) {
                float v = acc[cb][q];
                if (bias) v += bias[col];
                if (dotanh) v = tanhf(v);
                out[(size_t)row * N + col] = v;
            }
        }
    }
}

// ---------------- gsum = label_p + node_t[trace] + prog_t (in-place) ----------------
__global__ void k_addgi(float* __restrict__ lp, const float* __restrict__ node_t,
                        const float* __restrict__ prog_t, const int* __restrict__ trace) {
    int idx = blockIdx.x * 256 + threadIdx.x;
    const int NG4 = G3 / 4;
    if (idx < T1 * BB * NG4) {
        int g4 = idx % NG4;
        int rest = idx / NG4;
        int b = rest % BB;
        int i = rest / BB;
        int node = trace[b * TT + i];
        float4 v = *(float4*)(lp + (size_t)idx * 4);
        float4 nt = *(const float4*)(node_t + (size_t)node * G3 + g4 * 4);
        float4 pt = *(const float4*)(prog_t + (size_t)b * G3 + g4 * 4);
        v.x += nt.x + pt.x; v.y += nt.y + pt.y; v.z += nt.z + pt.z; v.w += nt.w + pt.w;
        *(float4*)(lp + (size_t)idx * 4) = v;
    }
}

// ---------------- GRU recurrence: partial LDS-resident weights ----------------
// 64 blocks x 512 thr, dynamic LDS 157,184 B. Thread (k = tid>>1, s = tid&1).
// Resident in LDS (transposed, conflict-free): gate-r all 64 words + gate-z first 12 words.
// Streamed from L2 per step: gate-z 52 words + gate-n 64 words (232 KB/block/step).
#define WRES_Z 3
__global__ __launch_bounds__(512, 2) void rec5L_kernel(
    const float* __restrict__ h0, const _Float16* __restrict__ whh16, const float* __restrict__ bhh,
    const float* __restrict__ gsum, float* __restrict__ store)
{
    extern __shared__ unsigned smem[];
    unsigned* wlds = smem;                        // [76 * 512]
    float* hs32 = (float*)(smem + 76 * 512);      // [256]
    _Float16* hs16 = (_Float16*)(hs32 + 256);     // [256]

    const int tid = threadIdx.x;
    const int s = tid & 1;
    const int k = tid >> 1;
    const int b = blockIdx.x;

    if (tid < HID) {
        float v = h0[(size_t)b * HID + tid];
        hs32[tid] = v;
        hs16[tid] = (_Float16)v;
    }

    union H8 { uint4 u; h2_t h[4]; };
    const uint4* wrp = (const uint4*)(whh16 + (size_t)k * HID + s * 128);
    const uint4* wzp = (const uint4*)(whh16 + (size_t)(HID + k) * HID + s * 128);
    const uint4* wnp = (const uint4*)(whh16 + (size_t)(2 * HID + k) * HID + s * 128);

    // stage resident weights (one-time)
#pragma unroll
    for (int cc = 0; cc < 16; cc++) {
        uint4 t = wrp[cc];
        wlds[(4 * cc + 0) * 512 + tid] = t.x;
        wlds[(4 * cc + 1) * 512 + tid] = t.y;
        wlds[(4 * cc + 2) * 512 + tid] = t.z;
        wlds[(4 * cc + 3) * 512 + tid] = t.w;
    }
#pragma unroll
    for (int cc = 0; cc < WRES_Z; cc++) {
        uint4 t = wzp[cc];
        wlds[(64 + 4 * cc + 0) * 512 + tid] = t.x;
        wlds[(64 + 4 * cc + 1) * 512 + tid] = t.y;
        wlds[(64 + 4 * cc + 2) * 512 + tid] = t.z;
        wlds[(64 + 4 * cc + 3) * 512 + tid] = t.w;
    }
    const float bhr = bhh[k], bhz = bhh[HID + k], bhn = bhh[2 * HID + k];
    __syncthreads();

    float gr_c = 0.f, gz_c = 0.f, gn_c = 0.f;
    if (s == 0) {
        const float* lp = gsum + (size_t)b * G3;
        gr_c = lp[k]; gz_c = lp[HID + k]; gn_c = lp[2 * HID + k];
    }

    for (int i = 0; i < T1; i++) {
        float gr_n = 0.f, gz_n = 0.f, gn_n = 0.f;
        if (s == 0 && i + 1 < T1) {
            const float* lp = gsum + ((size_t)(i + 1) * BB + b) * G3;
            gr_n = lp[k]; gz_n = lp[HID + k]; gn_n = lp[2 * HID + k];
        }
        const uint4* h8 = (const uint4*)(hs16 + s * 128);
        float ar = 0.f, az = 0.f, an = 0.f;
#pragma unroll
        for (int cc = 0; cc < 16; cc++) {
            H8 hv; hv.u = h8[cc];
            // gate r: LDS-resident
            unsigned r0 = wlds[(4 * cc + 0) * 512 + tid];
            unsigned r1 = wlds[(4 * cc + 1) * 512 + tid];
            unsigned r2 = wlds[(4 * cc + 2) * 512 + tid];
            unsigned r3 = wlds[(4 * cc + 3) * 512 + tid];
            ar = dot2(__builtin_bit_cast(h2_t, r0), hv.h[0], ar);
            ar = dot2(__builtin_bit_cast(h2_t, r1), hv.h[1], ar);
            ar = dot2(__builtin_bit_cast(h2_t, r2), hv.h[2], ar);
            ar = dot2(__builtin_bit_cast(h2_t, r3), hv.h[3], ar);
            // gate n: streamed
            uint4 tn = wnp[cc];
            an = dot2(__builtin_bit_cast(h2_t, tn.x), hv.h[0], an);
            an = dot2(__builtin_bit_cast(h2_t, tn.y), hv.h[1], an);
            an = dot2(__builtin_bit_cast(h2_t, tn.z), hv.h[2], an);
            an = dot2(__builtin_bit_cast(h2_t, tn.w), hv.h[3], an);
            // gate z: resident for cc<WRES_Z, streamed otherwise
            if (cc < WRES_Z) {
                unsigned z0 = wlds[(64 + 4 * cc + 0) * 512 + tid];
                unsigned z1 = wlds[(64 + 4 * cc + 1) * 512 + tid];
                unsigned z2 = wlds[(64 + 4 * cc + 2) * 512 + tid];
                unsigned z3 = wlds[(64 + 4 * cc + 3) * 512 + tid];
                az = dot2(__builtin_bit_cast(h2_t, z0), hv.h[0], az);
                az = dot2(__builtin_bit_cast(h2_t, z1), hv.h[1], az);
                az = dot2(__builtin_bit_cast(h2_t, z2), hv.h[2], az);
                az = dot2(__builtin_bit_cast(h2_t, z3), hv.h[3], az);
            } else {
                uint4 tz = wzp[cc];
                az = dot2(__builtin_bit_cast(h2_t, tz.x), hv.h[0], az);
                az = dot2(__builtin_bit_cast(h2_t, tz.y), hv.h[1], az);
                az = dot2(__builtin_bit_cast(h2_t, tz.z), hv.h[2], az);
                az = dot2(__builtin_bit_cast(h2_t, tz.w), hv.h[3], az);
            }
        }
        ar += __shfl_xor(ar, 1); az += __shfl_xor(az, 1); an += __shfl_xor(an, 1);
        __syncthreads();
        if (s == 0) {
            float r = 1.f / (1.f + expf(-(gr_c + ar + bhr)));
            float z = 1.f / (1.f + expf(-(gz_c + az + bhz)));
            float n = tanhf(gn_c + r * (an + bhn));
            float hold = hs32[k];
            float hnew = (1.f - z) * n + z * hold;
            hs32[k] = hnew;
            hs16[k] = (_Float16)hnew;
            store[((size_t)b * T1 + i) * HID + k] = hnew;
        }
        __syncthreads();
        gr_c = gr_n; gz_c = gz_n; gn_c = gn_n;
    }
}

// ---------------- scores = U @ ws2^T ----------------
__global__ void k_scores(const float* __restrict__ U, const float* __restrict__ ws2, float* __restrict__ sbuf) {
    int flat = blockIdx.x * 256 + threadIdx.x;
    if (flat < BB * T1 * NHEADS) {
        int m = flat / NHEADS, h = flat % NHEADS;
        const float* u = U + (size_t)m * HID;
        const float* w = ws2 + h * HID;
        float acc = 0.f;
        for (int c = 0; c < HID; c += 4) {
            float4 u4 = *(const float4*)(u + c);
            float4 w4 = *(const float4*)(w + c);
            acc += u4.x * w4.x + u4.y * w4.y + u4.z * w4.z + u4.w * w4.w;
        }
        sbuf[flat] = acc;
    }
}

// ---------------- per-(b,h) global max + exp + prefix denominators ----------------
__global__ void k_softmax_scan(const float* __restrict__ sbuf, float* __restrict__ ebuf, float* __restrict__ rD) {
    int tid = threadIdx.x;
    if (tid < BB * NHEADS) {
        int b = tid / NHEADS, h = tid % NHEADS;
        const float* s = sbuf + (size_t)b * T1 * NHEADS + h;
        float m = -1e30f;
        for (int t = 0; t < T1; t++) m = fmaxf(m, s[t * NHEADS]);
        float d = 0.f;
        for (int t = 0; t < T1; t++) {
            float e = expf(s[t * NHEADS] - m);
            ebuf[(b * T1 + t) * NHEADS + h] = e;
            d += e;
            rD[(b * T1 + t) * NHEADS + h] = 1.f / d;
        }
    }
}

// ---------------- alphas output ----------------
__global__ void k_alphas(const float* __restrict__ ebuf, const float* __restrict__ rD, float* __restrict__ alph) {
    int flat = blockIdx.x * 256 + threadIdx.x;
    const int TOT = T1 * BB * T1 * NHEADS;
    if (flat < TOT) {
        int i = flat / (BB * T1 * NHEADS);
        int rem = flat % (BB * T1 * NHEADS);
        int b = rem / (T1 * NHEADS);
        int rem2 = rem % (T1 * NHEADS);
        int t = rem2 / NHEADS, h = rem2 % NHEADS;
        float v = 0.f;
        if (t <= i) v = ebuf[(b * T1 + t) * NHEADS + h] * rD[(b * T1 + i) * NHEADS + h];
        alph[flat] = v;
    }
}

// ---------------- ctx prefix scan ----------------
__global__ __launch_bounds__(256) void k_ctx(const float* __restrict__ ebuf, const float* __restrict__ rD,
                                             const float* __restrict__ store, float* __restrict__ ctx) {
    __shared__ float eL[T1], rL[T1];
    int b = blockIdx.x / NHEADS, h = blockIdx.x % NHEADS;
    int k = threadIdx.x;
    if (k < T1) {
        eL[k] = ebuf[(b * T1 + k) * NHEADS + h];
        rL[k] = rD[(b * T1 + k) * NHEADS + h];
    }
    __syncthreads();
    float acc = 0.f;
#pragma unroll 4
    for (int t = 0; t < T1; t++) {
        acc += eL[t] * store[((size_t)b * T1 + t) * HID + k];
        ctx[((size_t)t * BB + b) * ATT + h * HID + k] = acc * rL[t];
    }
}

// ---------------- expert bucketing (R9-proven) ----------------
__global__ void k_count(const int* __restrict__ trace, int* __restrict__ cnt) {
    int idx = blockIdx.x * 256 + threadIdx.x;
    if (idx < T1 * BB) {
        int i = idx >> 6, b = idx & 63;
        int node = trace[b * TT + i + 1];
        atomicAdd(&cnt[node], 1);
    }
}

__global__ __launch_bounds__(256) void k_scan(const int* __restrict__ cnt, int* __restrict__ boff) {
    __shared__ int part[256];
    int t = threadIdx.x;
    int s0 = 0;
#pragma unroll
    for (int j = 0; j < 8; j++) { int idx = t * 8 + j; if (idx < NNODE + 1) s0 += cnt[idx]; }
    part[t] = s0;
    __syncthreads();
    for (int off = 1; off < 256; off <<= 1) {
        int u = (t >= off) ? part[t - off] : 0;
        __syncthreads();
        part[t] += u;
        __syncthreads();
    }
    int run = part[t] - s0;
    for (int j = 0; j < 8; j++) {
        int idx = t * 8 + j;
        if (idx < NNODE + 1) { boff[idx] = run; run += cnt[idx]; }
    }
    if (t == 255) boff[NNODE + 1] = part[255];
}

__global__ void k_scatter(const int* __restrict__ trace, const int* __restrict__ boff,
                          int* __restrict__ cur, int* __restrict__ items) {
    int idx = blockIdx.x * 256 + threadIdx.x;
    if (idx < T1 * BB) {
        int i = idx >> 6, b = idx & 63;
        int node = trace[b * TT + i + 1];
        int pos = atomicAdd(&cur[node], 1);
        items[boff[node] + pos] = idx;
    }
}

// one block per expert: stream weights once for all its items (chunks of 8)
__global__ __launch_bounds__(256) void k_pred2(
    const float* __restrict__ ctx, const float* __restrict__ pw, const float* __restrict__ pb,
    const int* __restrict__ boff, const int* __restrict__ items, float* __restrict__ outs)
{
    __shared__ float cl[8][ATT];
    __shared__ float red[16][16][8];
    int e = blockIdx.x;
    int start = boff[e], end = boff[e + 1];
    if (start == end) return;
    int tid = threadIdx.x;
    int d = tid & 15, ks = tid >> 4;
    const float* w = pw + (size_t)e * ATT * DD;
    float biasv = pb[e * DD + d];
    for (int c0 = start; c0 < end; c0 += 8) {
        int cn = min(8, end - c0);
        for (int j = 0; j < cn; j++) {
            int item = items[c0 + j];
            const float* cp = ctx + (size_t)item * ATT;
            for (int x = tid; x < ATT; x += 256) cl[j][x] = cp[x];
        }
        __syncthreads();
        float acc[8];
#pragma unroll
        for (int j = 0; j < 8; j++) acc[j] = 0.f;
        for (int kx = ks * 80; kx < ks * 80 + 80; kx++) {
            float wv = w[kx * DD + d];
#pragma unroll
            for (int j = 0; j < 8; j++) acc[j] += cl[j][kx] * wv;
        }
#pragma unroll
        for (int j = 0; j < 8; j++) red[ks][d][j] = acc[j];
        __syncthreads();
#pragma unroll
        for (int st = 8; st >= 1; st >>= 1) {
            if (ks < st) {
#pragma unroll
                for (int j = 0; j < 8; j++) red[ks][d][j] += red[ks + st][d][j];
            }
            __syncthreads();
        }
        if (ks == 0) {
            for (int j = 0; j < cn; j++) {
                int item = items[c0 + j];
                outs[(size_t)item * DD + d] = red[0][d][j] + biasv;
            }
        }
        __syncthreads();
    }
}

extern "C" void kernel_launch(void* const* d_in, const int* in_sizes, int n_in,
                              void* d_out, int out_size, void* d_ws, size_t ws_size,
                              hipStream_t stream) {
    const float* program_emb = (const float*)d_in[0];
    const float* h0       = (const float*)d_in[1];
    const float* node_emb = (const float*)d_in[2];
    const float* label_emb= (const float*)d_in[3];
    const float* w_ih     = (const float*)d_in[4];
    const float* w_hh     = (const float*)d_in[5];
    const float* b_ih     = (const float*)d_in[6];
    const float* b_hh     = (const float*)d_in[7];
    const float* ws1      = (const float*)d_in[8];
    const float* ws2      = (const float*)d_in[9];
    const float* pred_w   = (const float*)d_in[10];
    const float* pred_b   = (const float*)d_in[11];
    const int*   trace    = (const int*)d_in[12];
    const int*   na       = (const int*)d_in[13];

    // ---- R9-proven layout (floats), UNCHANGED ----
    float*          ws      = (float*)d_ws;
    float*          store   = ws + 0;           // [0 .. 2,080,768)
    unsigned short* wihT16  = (unsigned short*)(ws + 2080768);   // dead after Ubuf mgemm
    unsigned short* ws1T16  = (unsigned short*)(ws + 2409472);   // dead after Ubuf mgemm
    float*          prog_t  = ws + 2803712;
    float*          node_t  = ws + 2852864;
    float*          sbuf    = ws + 4389632;
    float*          ebuf    = ws + 4430272;
    float*          rD      = ws + 4470912;
    float*          label_p = ws + 4511568;     // gsum in-place; dead after rec5L
    float*          Ubuf    = ws + 10753872;    // dead after k_scores
    _Float16*       whh16   = (_Float16*)(ws + 12834640);  // dead after rec5L
    float*          ctx     = ws + 4511568;     // [.. 14,915,408) aliases label_p/Ubuf/whh16
    int*            cnt     = (int*)(ws + 2080768);         // over dead wihT16
    int*            cur     = cnt + 2048;
    int*            boff    = cur + 2048;
    int*            items   = boff + 2048;

    float* outs = (float*)d_out;
    float* alph = outs + T1 * BB * DD;

    // allow 157 KB dynamic LDS for the recurrence (idempotent host-side call)
    hipFuncSetAttribute((const void*)rec5L_kernel,
                        hipFuncAttributeMaxDynamicSharedMemorySize, 160 * 1024);
    const size_t REC_LDS = (size_t)76 * 512 * 4 + 256 * 4 + 256 * 2;   // 157,184 B

    // P1: static precompute (bf16 MFMA GEMMs)
    k_tcvt<<<2568, 256, 0, stream>>>(w_ih, wihT16, G3, 856);
    k_tcvt<<<256, 256, 0, stream>>>(ws1, ws1T16, HID, HID);
    k_cvt<<<768, 256, 0, stream>>>(w_hh, whh16, G3 * HID);
    k_mgemm<<<12,   256, 0, stream>>>(program_emb, wihT16, prog_t, b_ih,   nullptr, nullptr, 0, 64,   256, G3,  256, 12, 300, G3, 0);
    k_mgemm<<<384,  256, 0, stream>>>(node_emb,    wihT16, node_t, nullptr, nullptr, nullptr, 0, 2001, 300, G3,  300, 12, 556, G3, 0);
    k_mgemm<<<1524, 256, 0, stream>>>(label_emb,   wihT16, label_p, nullptr, trace,  na,      2, 8128, 300, G3,  300, 12, 0,   G3, 0);
    k_addgi<<<6096, 256, 0, stream>>>(label_p, node_t, prog_t, trace);

    // P2: sequential recurrence — partial LDS-resident weights
    rec5L_kernel<<<64, 512, REC_LDS, stream>>>(h0, whh16, b_hh, label_p, store);

    // P3: parallel attention + prediction
    k_mgemm<<<508, 256, 0, stream>>>(store, ws1T16, Ubuf, nullptr, nullptr, nullptr, 0, 8128, 256, HID, 256, 4, 0, HID, 1);
    k_scores<<<159, 256, 0, stream>>>(Ubuf, ws2, sbuf);
    k_softmax_scan<<<1, 512, 0, stream>>>(sbuf, ebuf, rD);
    k_alphas<<<20162, 256, 0, stream>>>(ebuf, rD, alph);
    k_ctx<<<320, 256, 0, stream>>>(ebuf, rD, store, ctx);

    // expert-bucketed prediction (R9-proven)
    hipMemsetAsync(cnt, 0, 2 * 2048 * sizeof(int), stream);
    k_count<<<32, 256, 0, stream>>>(trace, cnt);
    k_scan<<<1, 256, 0, stream>>>(cnt, boff);
    k_scatter<<<32, 256, 0, stream>>>(trace, boff, cur, items);
    k_pred2<<<NNODE + 1, 256, 0, stream>>>(ctx, pred_w, pred_b, boff, items, outs);
}

// Round 11
// 555.034 us; speedup vs baseline: 2.3082x; 2.3082x over previous
//
#include <hip/hip_runtime.h>
#include <hip/hip_bf16.h>
#include <math.h>

#define BB 64
#define TT 128
#define T1 127
#define NNODE 2000
#define EE 300
#define HID 256
#define NHEADS 5
#define DD 16
#define G3 768
#define ATT 1280

typedef _Float16 h2_t __attribute__((ext_vector_type(2)));
typedef short short8 __attribute__((ext_vector_type(8)));
typedef float f32x4 __attribute__((ext_vector_type(4)));

__device__ __forceinline__ float dot2(h2_t a, h2_t b, float c) {
    asm("v_dot2_f32_f16 %0, %1, %2, %0" : "+v"(c) : "v"(a), "v"(b));
    return c;
}

__device__ __forceinline__ unsigned short f2bf(float f) {
    unsigned u = __float_as_uint(f);
    unsigned r = (u + 0x7FFFu + ((u >> 16) & 1u)) >> 16;   // RNE
    return (unsigned short)r;
}

// ---------------- transpose + f32->bf16 ----------------
__global__ void k_tcvt(const float* __restrict__ src, unsigned short* __restrict__ dst, int R, int C) {
    int idx = blockIdx.x * 256 + threadIdx.x;
    if (idx < R * C) {
        int r = idx / C, c = idx % C;
        dst[c * R + r] = f2bf(src[idx]);
    }
}

// ---------------- f32 -> f16 convert ----------------
__global__ void k_cvt(const float* __restrict__ src, _Float16* __restrict__ dst, int n) {
    int i = blockIdx.x * 256 + threadIdx.x;
    if (i < n) dst[i] = (_Float16)src[i];
}

// ---------------- bf16 MFMA GEMM (R6-proven) ----------------
__global__ __launch_bounds__(256) void k_mgemm(
    const float* __restrict__ A, const unsigned short* __restrict__ B16,
    float* __restrict__ out, const float* __restrict__ bias,
    const int* __restrict__ trace, const int* __restrict__ na,
    int mode, int M, int K, int N, int strideA, int ntiles, int brow0, int Bld, int dotanh)
{
    __shared__ short As[64][40];
    __shared__ short Bt[64][40];
    __shared__ int baseLds[64];
    __shared__ int validLds[64];
    int tid = threadIdx.x;
    int bm = blockIdx.x / ntiles, bn = blockIdx.x % ntiles;
    int m0 = bm * 64, n0 = bn * 64;
    if (tid < 64) {
        int m = m0 + tid;
        int valid = (m < M) ? 1 : 0;
        int base = 0;
        if (valid) {
            if (mode == 2) {
                int i = m >> 6, bb = m & 63;
                int node = trace[bb * TT + i];
                int asg = (node < NNODE) ? na[bb * NNODE + node] : 0;
                base = (node * DD + asg) * EE;
            } else {
                base = m * strideA;
            }
        }
        baseLds[tid] = base;
        validLds[tid] = valid;
    }
    __syncthreads();

    int wv = tid >> 6, l = tid & 63;
    int lr = l & 15, lg = l >> 4;
    f32x4 acc[4];
#pragma unroll
    for (int cb = 0; cb < 4; cb++) acc[cb] = (f32x4){0.f, 0.f, 0.f, 0.f};

    int ar = tid >> 2, aq = tid & 3;
    int bk = tid >> 3, bq = tid & 7;
    int nsteps = (K + 31) >> 5;
    for (int it = 0; it < nsteps; it++) {
        int kk = it * 32;
        {
            int base = baseLds[ar], val = validLds[ar];
            short8 t1;
#pragma unroll
            for (int j = 0; j < 8; j++) {
                int kx = kk + aq * 8 + j;
                float v = (val && kx < K) ? A[(size_t)base + kx] : 0.f;
                t1[j] = (short)f2bf(v);
            }
            *(short8*)&As[ar][aq * 8] = t1;
        }
        {
            int kx = kk + bk;
            short8 t2;
            if (kx < K) {
                t2 = *(const short8*)(B16 + (size_t)(brow0 + kx) * Bld + n0 + bq * 8);
            } else {
#pragma unroll
                for (int j = 0; j < 8; j++) t2[j] = 0;
            }
#pragma unroll
            for (int j = 0; j < 8; j++) Bt[bq * 8 + j][bk] = t2[j];
        }
        __syncthreads();
        short8 a = *(const short8*)&As[wv * 16 + lr][lg * 8];
#pragma unroll
        for (int cb = 0; cb < 4; cb++) {
            short8 bfr = *(const short8*)&Bt[cb * 16 + lr][lg * 8];
            acc[cb] = __builtin_amdgcn_mfma_f32_16x16x32_bf16(a, bfr, acc[cb], 0, 0, 0);
        }
        __syncthreads();
    }
#pragma unroll
    for (int cb = 0; cb < 4; cb++) {
        int col = n0 + cb * 16 + lr;
#pragma unroll
        for (int q = 0; q < 4; q++) {
            int row = m0 + wv * 16 + lg * 4 + q;
            if (row < M) {
                float v = acc[cb][q];
                if (bias) v += bias[col];
                if (dotanh) v = tanhf(v);
                out[(size_t)row * N + col] = v;
            }
        }
    }
}

// ---------------- gsum = label_p + node_t[trace] + prog_t (in-place) ----------------
__global__ void k_addgi(float* __restrict__ lp, const float* __restrict__ node_t,
                        const float* __restrict__ prog_t, const int* __restrict__ trace) {
    int idx = blockIdx.x * 256 + threadIdx.x;
    const int NG4 = G3 / 4;
    if (idx < T1 * BB * NG4) {
        int g4 = idx % NG4;
        int rest = idx / NG4;
        int b = rest % BB;
        int i = rest / BB;
        int node = trace[b * TT + i];
        float4 v = *(float4*)(lp + (size_t)idx * 4);
        float4 nt = *(const float4*)(node_t + (size_t)node * G3 + g4 * 4);
        float4 pt = *(const float4*)(prog_t + (size_t)b * G3 + g4 * 4);
        v.x += nt.x + pt.x; v.y += nt.y + pt.y; v.z += nt.z + pt.z; v.w += nt.w + pt.w;
        *(float4*)(lp + (size_t)idx * 4) = v;
    }
}

// ---------------- GRU recurrence: rec4 structure + gate-r in LDS ----------------
// 64 blocks x 512 thr. Thread (k = tid>>1, s = tid&1), K-half split, shfl_xor(1) combine.
// Gate-r weights (64 words/thread = 128 KB/block) staged once in dynamic LDS
// (transposed: wlds[word*512 + tid], per-lane stride 4B -> conflict-free).
// Gates z,n remain rec4's pre-declared H8 array pattern (proven load pipelining).
__global__ __launch_bounds__(512, 2) void rec7_kernel(
    const float* __restrict__ h0, const _Float16* __restrict__ whh16, const float* __restrict__ bhh,
    const float* __restrict__ gsum, float* __restrict__ store)
{
    extern __shared__ unsigned smem[];
    unsigned* wlds = smem;                        // [64 * 512]
    float* hs32 = (float*)(smem + 64 * 512);      // [256]
    _Float16* hs16 = (_Float16*)(hs32 + 256);     // [256]

    const int tid = threadIdx.x;
    const int s = tid & 1;
    const int k = tid >> 1;
    const int b = blockIdx.x;

    if (tid < HID) {
        float v = h0[(size_t)b * HID + tid];
        hs32[tid] = v;
        hs16[tid] = (_Float16)v;
    }

    union H8 { uint4 u; h2_t h[4]; };
    // stage gate-r into LDS (one-time)
    {
        const uint4* wrp = (const uint4*)(whh16 + (size_t)k * HID + s * 128);
#pragma unroll
        for (int cc = 0; cc < 16; cc++) {
            uint4 t = wrp[cc];
            wlds[(4 * cc + 0) * 512 + tid] = t.x;
            wlds[(4 * cc + 1) * 512 + tid] = t.y;
            wlds[(4 * cc + 2) * 512 + tid] = t.z;
            wlds[(4 * cc + 3) * 512 + tid] = t.w;
        }
    }
    // gates z,n: rec4's proven pre-declared array pattern
    H8 wZ[16], wN[16];
    {
        const uint4* wzp = (const uint4*)(whh16 + (size_t)(HID + k) * HID + s * 128);
        const uint4* wnp = (const uint4*)(whh16 + (size_t)(2 * HID + k) * HID + s * 128);
#pragma unroll
        for (int cc = 0; cc < 16; cc++) { wZ[cc].u = wzp[cc]; wN[cc].u = wnp[cc]; }
    }
    const float bhr = bhh[k], bhz = bhh[HID + k], bhn = bhh[2 * HID + k];
    __syncthreads();

    float gr_c = 0.f, gz_c = 0.f, gn_c = 0.f;
    if (s == 0) {
        const float* lp = gsum + (size_t)b * G3;
        gr_c = lp[k]; gz_c = lp[HID + k]; gn_c = lp[2 * HID + k];
    }

    for (int i = 0; i < T1; i++) {
        float gr_n = 0.f, gz_n = 0.f, gn_n = 0.f;
        if (s == 0 && i + 1 < T1) {
            const float* lp = gsum + ((size_t)(i + 1) * BB + b) * G3;
            gr_n = lp[k]; gz_n = lp[HID + k]; gn_n = lp[2 * HID + k];
        }
        const uint4* h8 = (const uint4*)(hs16 + s * 128);
        float ar = 0.f, az = 0.f, an = 0.f;
#pragma unroll
        for (int cc = 0; cc < 16; cc++) {
            H8 hv; hv.u = h8[cc];
            // gate r from LDS (conflict-free b32 reads)
            unsigned r0 = wlds[(4 * cc + 0) * 512 + tid];
            unsigned r1 = wlds[(4 * cc + 1) * 512 + tid];
            unsigned r2 = wlds[(4 * cc + 2) * 512 + tid];
            unsigned r3 = wlds[(4 * cc + 3) * 512 + tid];
            ar = dot2(__builtin_bit_cast(h2_t, r0), hv.h[0], ar);
            ar = dot2(__builtin_bit_cast(h2_t, r1), hv.h[1], ar);
            ar = dot2(__builtin_bit_cast(h2_t, r2), hv.h[2], ar);
            ar = dot2(__builtin_bit_cast(h2_t, r3), hv.h[3], ar);
#pragma unroll
            for (int j = 0; j < 4; j++) {
                az = dot2(wZ[cc].h[j], hv.h[j], az);
                an = dot2(wN[cc].h[j], hv.h[j], an);
            }
        }
        ar += __shfl_xor(ar, 1); az += __shfl_xor(az, 1); an += __shfl_xor(an, 1);
        __syncthreads();
        if (s == 0) {
            float r = 1.f / (1.f + expf(-(gr_c + ar + bhr)));
            float z = 1.f / (1.f + expf(-(gz_c + az + bhz)));
            float n = tanhf(gn_c + r * (an + bhn));
            float hold = hs32[k];
            float hnew = (1.f - z) * n + z * hold;
            hs32[k] = hnew;
            hs16[k] = (_Float16)hnew;
            store[((size_t)b * T1 + i) * HID + k] = hnew;
        }
        __syncthreads();
        gr_c = gr_n; gz_c = gz_n; gn_c = gn_n;
    }
}

// ---------------- scores = U @ ws2^T ----------------
__global__ void k_scores(const float* __restrict__ U, const float* __restrict__ ws2, float* __restrict__ sbuf) {
    int flat = blockIdx.x * 256 + threadIdx.x;
    if (flat < BB * T1 * NHEADS) {
        int m = flat / NHEADS, h = flat % NHEADS;
        const float* u = U + (size_t)m * HID;
        const float* w = ws2 + h * HID;
        float acc = 0.f;
        for (int c = 0; c < HID; c += 4) {
            float4 u4 = *(const float4*)(u + c);
            float4 w4 = *(const float4*)(w + c);
            acc += u4.x * w4.x + u4.y * w4.y + u4.z * w4.z + u4.w * w4.w;
        }
        sbuf[flat] = acc;
    }
}

// ---------------- per-(b,h) global max + exp + prefix denominators ----------------
__global__ void k_softmax_scan(const float* __restrict__ sbuf, float* __restrict__ ebuf, float* __restrict__ rD) {
    int tid = threadIdx.x;
    if (tid < BB * NHEADS) {
        int b = tid / NHEADS, h = tid % NHEADS;
        const float* s = sbuf + (size_t)b * T1 * NHEADS + h;
        float m = -1e30f;
        for (int t = 0; t < T1; t++) m = fmaxf(m, s[t * NHEADS]);
        float d = 0.f;
        for (int t = 0; t < T1; t++) {
            float e = expf(s[t * NHEADS] - m);
            ebuf[(b * T1 + t) * NHEADS + h] = e;
            d += e;
            rD[(b * T1 + t) * NHEADS + h] = 1.f / d;
        }
    }
}

// ---------------- alphas output ----------------
__global__ void k_alphas(const float* __restrict__ ebuf, const float* __restrict__ rD, float* __restrict__ alph) {
    int flat = blockIdx.x * 256 + threadIdx.x;
    const int TOT = T1 * BB * T1 * NHEADS;
    if (flat < TOT) {
        int i = flat / (BB * T1 * NHEADS);
        int rem = flat % (BB * T1 * NHEADS);
        int b = rem / (T1 * NHEADS);
        int rem2 = rem % (T1 * NHEADS);
        int t = rem2 / NHEADS, h = rem2 % NHEADS;
        float v = 0.f;
        if (t <= i) v = ebuf[(b * T1 + t) * NHEADS + h] * rD[(b * T1 + i) * NHEADS + h];
        alph[flat] = v;
    }
}

// ---------------- ctx prefix scan ----------------
__global__ __launch_bounds__(256) void k_ctx(const float* __restrict__ ebuf, const float* __restrict__ rD,
                                             const float* __restrict__ store, float* __restrict__ ctx) {
    __shared__ float eL[T1], rL[T1];
    int b = blockIdx.x / NHEADS, h = blockIdx.x % NHEADS;
    int k = threadIdx.x;
    if (k < T1) {
        eL[k] = ebuf[(b * T1 + k) * NHEADS + h];
        rL[k] = rD[(b * T1 + k) * NHEADS + h];
    }
    __syncthreads();
    float acc = 0.f;
#pragma unroll 4
    for (int t = 0; t < T1; t++) {
        acc += eL[t] * store[((size_t)b * T1 + t) * HID + k];
        ctx[((size_t)t * BB + b) * ATT + h * HID + k] = acc * rL[t];
    }
}

// ---------------- expert bucketing (R9-proven) ----------------
__global__ void k_count(const int* __restrict__ trace, int* __restrict__ cnt) {
    int idx = blockIdx.x * 256 + threadIdx.x;
    if (idx < T1 * BB) {
        int i = idx >> 6, b = idx & 63;
        int node = trace[b * TT + i + 1];
        atomicAdd(&cnt[node], 1);
    }
}

__global__ __launch_bounds__(256) void k_scan(const int* __restrict__ cnt, int* __restrict__ boff) {
    __shared__ int part[256];
    int t = threadIdx.x;
    int s0 = 0;
#pragma unroll
    for (int j = 0; j < 8; j++) { int idx = t * 8 + j; if (idx < NNODE + 1) s0 += cnt[idx]; }
    part[t] = s0;
    __syncthreads();
    for (int off = 1; off < 256; off <<= 1) {
        int u = (t >= off) ? part[t - off] : 0;
        __syncthreads();
        part[t] += u;
        __syncthreads();
    }
    int run = part[t] - s0;
    for (int j = 0; j < 8; j++) {
        int idx = t * 8 + j;
        if (idx < NNODE + 1) { boff[idx] = run; run += cnt[idx]; }
    }
    if (t == 255) boff[NNODE + 1] = part[255];
}

__global__ void k_scatter(const int* __restrict__ trace, const int* __restrict__ boff,
                          int* __restrict__ cur, int* __restrict__ items) {
    int idx = blockIdx.x * 256 + threadIdx.x;
    if (idx < T1 * BB) {
        int i = idx >> 6, b = idx & 63;
        int node = trace[b * TT + i + 1];
        int pos = atomicAdd(&cur[node], 1);
        items[boff[node] + pos] = idx;
    }
}

// one block per expert: stream weights once for all its items (chunks of 8)
__global__ __launch_bounds__(256) void k_pred2(
    const float* __restrict__ ctx, const float* __restrict__ pw, const float* __restrict__ pb,
    const int* __restrict__ boff, const int* __restrict__ items, float* __restrict__ outs)
{
    __shared__ float cl[8][ATT];
    __shared__ float red[16][16][8];
    int e = blockIdx.x;
    int start = boff[e], end = boff[e + 1];
    if (start == end) return;
    int tid = threadIdx.x;
    int d = tid & 15, ks = tid >> 4;
    const float* w = pw + (size_t)e * ATT * DD;
    float biasv = pb[e * DD + d];
    for (int c0 = start; c0 < end; c0 += 8) {
        int cn = min(8, end - c0);
        for (int j = 0; j < cn; j++) {
            int item = items[c0 + j];
            const float* cp = ctx + (size_t)item * ATT;
            for (int x = tid; x < ATT; x += 256) cl[j][x] = cp[x];
        }
        __syncthreads();
        float acc[8];
#pragma unroll
        for (int j = 0; j < 8; j++) acc[j] = 0.f;
        for (int kx = ks * 80; kx < ks * 80 + 80; kx++) {
            float wv = w[kx * DD + d];
#pragma unroll
            for (int j = 0; j < 8; j++) acc[j] += cl[j][kx] * wv;
        }
#pragma unroll
        for (int j = 0; j < 8; j++) red[ks][d][j] = acc[j];
        __syncthreads();
#pragma unroll
        for (int st = 8; st >= 1; st >>= 1) {
            if (ks < st) {
#pragma unroll
                for (int j = 0; j < 8; j++) red[ks][d][j] += red[ks + st][d][j];
            }
            __syncthreads();
        }
        if (ks == 0) {
            for (int j = 0; j < cn; j++) {
                int item = items[c0 + j];
                outs[(size_t)item * DD + d] = red[0][d][j] + biasv;
            }
        }
        __syncthreads();
    }
}

extern "C" void kernel_launch(void* const* d_in, const int* in_sizes, int n_in,
                              void* d_out, int out_size, void* d_ws, size_t ws_size,
                              hipStream_t stream) {
    const float* program_emb = (const float*)d_in[0];
    const float* h0       = (const float*)d_in[1];
    const float* node_emb = (const float*)d_in[2];
    const float* label_emb= (const float*)d_in[3];
    const float* w_ih     = (const float*)d_in[4];
    const float* w_hh     = (const float*)d_in[5];
    const float* b_ih     = (const float*)d_in[6];
    const float* b_hh     = (const float*)d_in[7];
    const float* ws1      = (const float*)d_in[8];
    const float* ws2      = (const float*)d_in[9];
    const float* pred_w   = (const float*)d_in[10];
    const float* pred_b   = (const float*)d_in[11];
    const int*   trace    = (const int*)d_in[12];
    const int*   na       = (const int*)d_in[13];

    // ---- R9-proven layout (floats), UNCHANGED ----
    float*          ws      = (float*)d_ws;
    float*          store   = ws + 0;           // [0 .. 2,080,768)
    unsigned short* wihT16  = (unsigned short*)(ws + 2080768);   // dead after Ubuf mgemm
    unsigned short* ws1T16  = (unsigned short*)(ws + 2409472);   // dead after Ubuf mgemm
    float*          prog_t  = ws + 2803712;
    float*          node_t  = ws + 2852864;
    float*          sbuf    = ws + 4389632;
    float*          ebuf    = ws + 4430272;
    float*          rD      = ws + 4470912;
    float*          label_p = ws + 4511568;     // gsum in-place; dead after rec7
    float*          Ubuf    = ws + 10753872;    // dead after k_scores
    _Float16*       whh16   = (_Float16*)(ws + 12834640);  // dead after rec7
    float*          ctx     = ws + 4511568;     // [.. 14,915,408) aliases label_p/Ubuf/whh16
    int*            cnt     = (int*)(ws + 2080768);         // over dead wihT16
    int*            cur     = cnt + 2048;
    int*            boff    = cur + 2048;
    int*            items   = boff + 2048;

    float* outs = (float*)d_out;
    float* alph = outs + T1 * BB * DD;

    // allow 133 KB dynamic LDS for the recurrence (idempotent host-side call)
    hipFuncSetAttribute((const void*)rec7_kernel,
                        hipFuncAttributeMaxDynamicSharedMemorySize, 160 * 1024);
    const size_t REC_LDS = (size_t)64 * 512 * 4 + 256 * 4 + 256 * 2;   // 132,608 B

    // P1: static precompute (bf16 MFMA GEMMs)
    k_tcvt<<<2568, 256, 0, stream>>>(w_ih, wihT16, G3, 856);
    k_tcvt<<<256, 256, 0, stream>>>(ws1, ws1T16, HID, HID);
    k_cvt<<<768, 256, 0, stream>>>(w_hh, whh16, G3 * HID);
    k_mgemm<<<12,   256, 0, stream>>>(program_emb, wihT16, prog_t, b_ih,   nullptr, nullptr, 0, 64,   256, G3,  256, 12, 300, G3, 0);
    k_mgemm<<<384,  256, 0, stream>>>(node_emb,    wihT16, node_t, nullptr, nullptr, nullptr, 0, 2001, 300, G3,  300, 12, 556, G3, 0);
    k_mgemm<<<1524, 256, 0, stream>>>(label_emb,   wihT16, label_p, nullptr, trace,  na,      2, 8128, 300, G3,  300, 12, 0,   G3, 0);
    k_addgi<<<6096, 256, 0, stream>>>(label_p, node_t, prog_t, trace);

    // P2: sequential recurrence — rec4 structure, gate-r LDS-resident
    rec7_kernel<<<64, 512, REC_LDS, stream>>>(h0, whh16, b_hh, label_p, store);

    // P3: parallel attention + prediction
    k_mgemm<<<508, 256, 0, stream>>>(store, ws1T16, Ubuf, nullptr, nullptr, nullptr, 0, 8128, 256, HID, 256, 4, 0, HID, 1);
    k_scores<<<159, 256, 0, stream>>>(Ubuf, ws2, sbuf);
    k_softmax_scan<<<1, 512, 0, stream>>>(sbuf, ebuf, rD);
    k_alphas<<<20162, 256, 0, stream>>>(ebuf, rD, alph);
    k_ctx<<<320, 256, 0, stream>>>(ebuf, rD, store, ctx);

    // expert-bucketed prediction (R9-proven)
    hipMemsetAsync(cnt, 0, 2 * 2048 * sizeof(int), stream);
    k_count<<<32, 256, 0, stream>>>(trace, cnt);
    k_scan<<<1, 256, 0, stream>>>(cnt, boff);
    k_scatter<<<32, 256, 0, stream>>>(trace, boff, cur, items);
    k_pred2<<<NNODE + 1, 256, 0, stream>>>(ctx, pred_w, pred_b, boff, items, outs);
}

// Round 12
// 388.179 us; speedup vs baseline: 3.3003x; 1.4298x over previous
//
#include <hip/hip_runtime.h>
#include <hip/hip_bf16.h>
#include <math.h>

#define BB 64
#define TT 128
#define T1 127
#define NNODE 2000
#define EE 300
#define HID 256
#define NHEADS 5
#define DD 16
#define G3 768
#define ATT 1280
#define SCALE_H 28.0f

typedef _Float16 h2_t __attribute__((ext_vector_type(2)));
typedef short short8 __attribute__((ext_vector_type(8)));
typedef float f32x4 __attribute__((ext_vector_type(4)));

__device__ __forceinline__ int dot4(int a, int b, int c) {
#if __has_builtin(__builtin_amdgcn_sdot4)
    return __builtin_amdgcn_sdot4(a, b, c, false);
#else
    int r;
    asm("v_dot4_i32_i8 %0, %1, %2, %3" : "=v"(r) : "v"(a), "v"(b), "v"(c));
    return r;
#endif
}

__device__ __forceinline__ unsigned short f2bf(float f) {
    unsigned u = __float_as_uint(f);
    unsigned r = (u + 0x7FFFu + ((u >> 16) & 1u)) >> 16;   // RNE
    return (unsigned short)r;
}

// ---------------- transpose + f32->bf16 ----------------
__global__ void k_tcvt(const float* __restrict__ src, unsigned short* __restrict__ dst, int R, int C) {
    int idx = blockIdx.x * 256 + threadIdx.x;
    if (idx < R * C) {
        int r = idx / C, c = idx % C;
        dst[c * R + r] = f2bf(src[idx]);
    }
}

// ---------------- per-row int8 quantization of w_hh ----------------
// row r: scale = max|w|/127; wq packed 4 cols/int; wsc[r] = scale
__global__ __launch_bounds__(64) void k_quant(const float* __restrict__ w, int* __restrict__ wq,
                                              float* __restrict__ wsc) {
    int row = blockIdx.x;   // 0..G3-1
    int t = threadIdx.x;    // 0..63
    const float* wr = w + (size_t)row * HID;
    float4 v = *(const float4*)(wr + t * 4);
    float m = fmaxf(fmaxf(fabsf(v.x), fabsf(v.y)), fmaxf(fabsf(v.z), fabsf(v.w)));
#pragma unroll
    for (int off = 1; off < 64; off <<= 1) m = fmaxf(m, __shfl_xor(m, off));
    float s = (m > 0.f) ? m * (1.0f / 127.0f) : 1.0f;
    float inv = 1.0f / s;
    int q0 = max(-127, min(127, __float2int_rn(v.x * inv)));
    int q1 = max(-127, min(127, __float2int_rn(v.y * inv)));
    int q2 = max(-127, min(127, __float2int_rn(v.z * inv)));
    int q3 = max(-127, min(127, __float2int_rn(v.w * inv)));
    wq[row * 64 + t] = (q0 & 0xFF) | ((q1 & 0xFF) << 8) | ((q2 & 0xFF) << 16) | ((q3 & 0xFF) << 24);
    if (t == 0) wsc[row] = s;
}

// ---------------- bf16 MFMA GEMM (R6-proven) ----------------
__global__ __launch_bounds__(256) void k_mgemm(
    const float* __restrict__ A, const unsigned short* __restrict__ B16,
    float* __restrict__ out, const float* __restrict__ bias,
    const int* __restrict__ trace, const int* __restrict__ na,
    int mode, int M, int K, int N, int strideA, int ntiles, int brow0, int Bld, int dotanh)
{
    __shared__ short As[64][40];
    __shared__ short Bt[64][40];
    __shared__ int baseLds[64];
    __shared__ int validLds[64];
    int tid = threadIdx.x;
    int bm = blockIdx.x / ntiles, bn = blockIdx.x % ntiles;
    int m0 = bm * 64, n0 = bn * 64;
    if (tid < 64) {
        int m = m0 + tid;
        int valid = (m < M) ? 1 : 0;
        int base = 0;
        if (valid) {
            if (mode == 2) {
                int i = m >> 6, bb = m & 63;
                int node = trace[bb * TT + i];
                int asg = (node < NNODE) ? na[bb * NNODE + node] : 0;
                base = (node * DD + asg) * EE;
            } else {
                base = m * strideA;
            }
        }
        baseLds[tid] = base;
        validLds[tid] = valid;
    }
    __syncthreads();

    int wv = tid >> 6, l = tid & 63;
    int lr = l & 15, lg = l >> 4;
    f32x4 acc[4];
#pragma unroll
    for (int cb = 0; cb < 4; cb++) acc[cb] = (f32x4){0.f, 0.f, 0.f, 0.f};

    int ar = tid >> 2, aq = tid & 3;
    int bk = tid >> 3, bq = tid & 7;
    int nsteps = (K + 31) >> 5;
    for (int it = 0; it < nsteps; it++) {
        int kk = it * 32;
        {
            int base = baseLds[ar], val = validLds[ar];
            short8 t1;
#pragma unroll
            for (int j = 0; j < 8; j++) {
                int kx = kk + aq * 8 + j;
                float v = (val && kx < K) ? A[(size_t)base + kx] : 0.f;
                t1[j] = (short)f2bf(v);
            }
            *(short8*)&As[ar][aq * 8] = t1;
        }
        {
            int kx = kk + bk;
            short8 t2;
            if (kx < K) {
                t2 = *(const short8*)(B16 + (size_t)(brow0 + kx) * Bld + n0 + bq * 8);
            } else {
#pragma unroll
                for (int j = 0; j < 8; j++) t2[j] = 0;
            }
#pragma unroll
            for (int j = 0; j < 8; j++) Bt[bq * 8 + j][bk] = t2[j];
        }
        __syncthreads();
        short8 a = *(const short8*)&As[wv * 16 + lr][lg * 8];
#pragma unroll
        for (int cb = 0; cb < 4; cb++) {
            short8 bfr = *(const short8*)&Bt[cb * 16 + lr][lg * 8];
            acc[cb] = __builtin_amdgcn_mfma_f32_16x16x32_bf16(a, bfr, acc[cb], 0, 0, 0);
        }
        __syncthreads();
    }
#pragma unroll
    for (int cb = 0; cb < 4; cb++) {
        int col = n0 + cb * 16 + lr;
#pragma unroll
        for (int q = 0; q < 4; q++) {
            int row = m0 + wv * 16 + lg * 4 + q;
            if (row < M) {
                float v = acc[cb][q];
                if (bias) v += bias[col];
                if (dotanh) v = tanhf(v);
                out[(size_t)row * N + col] = v;
            }
        }
    }
}

// ---------------- gsum = label_p + node_t[trace] + prog_t (in-place) ----------------
__global__ void k_addgi(float* __restrict__ lp, const float* __restrict__ node_t,
                        const float* __restrict__ prog_t, const int* __restrict__ trace) {
    int idx = blockIdx.x * 256 + threadIdx.x;
    const int NG4 = G3 / 4;
    if (idx < T1 * BB * NG4) {
        int g4 = idx % NG4;
        int rest = idx / NG4;
        int b = rest % BB;
        int i = rest / BB;
        int node = trace[b * TT + i];
        float4 v = *(float4*)(lp + (size_t)idx * 4);
        float4 nt = *(const float4*)(node_t + (size_t)node * G3 + g4 * 4);
        float4 pt = *(const float4*)(prog_t + (size_t)b * G3 + g4 * 4);
        v.x += nt.x + pt.x; v.y += nt.y + pt.y; v.z += nt.z + pt.z; v.w += nt.w + pt.w;
        *(float4*)(lp + (size_t)idx * 4) = v;
    }
}

// ---------------- GRU recurrence: int8 weights, register-resident (96 VGPR) ----------------
// rec4 structure: 64 blocks x 512 thr, thread (k = tid>>1, s = tid&1), shfl_xor(1) combine.
// Weights quantized per-row int8, packed 4/dword: 3 gates x 32 dwords/thread.
// h quantized to int8 (scale 28) in LDS each step; f32 state kept for the z-blend.
__global__ __launch_bounds__(512, 2) void rec8_kernel(
    const float* __restrict__ h0, const int* __restrict__ whh8q, const float* __restrict__ wsc,
    const float* __restrict__ bhh, const float* __restrict__ gsum, float* __restrict__ store)
{
    __shared__ float hs32[HID];
    __shared__ int hs8w[HID / 4];
    const int tid = threadIdx.x;
    const int s = tid & 1;
    const int k = tid >> 1;
    const int b = blockIdx.x;

    if (tid < HID) {
        float v = h0[(size_t)b * HID + tid];
        hs32[tid] = v;
        int q = max(-127, min(127, __float2int_rn(v * SCALE_H)));
        ((char*)hs8w)[tid] = (char)q;
    }

    int wR[32], wZ[32], wN[32];
    {
        const int* pr = whh8q + (size_t)k * 64 + s * 32;
        const int* pz = whh8q + (size_t)(HID + k) * 64 + s * 32;
        const int* pn = whh8q + (size_t)(2 * HID + k) * 64 + s * 32;
#pragma unroll
        for (int cc = 0; cc < 32; cc++) { wR[cc] = pr[cc]; wZ[cc] = pz[cc]; wN[cc] = pn[cc]; }
    }
    const float sR = wsc[k] * (1.0f / SCALE_H);
    const float sZ = wsc[HID + k] * (1.0f / SCALE_H);
    const float sN = wsc[2 * HID + k] * (1.0f / SCALE_H);
    const float bhr = bhh[k], bhz = bhh[HID + k], bhn = bhh[2 * HID + k];
    __syncthreads();

    float gr_c = 0.f, gz_c = 0.f, gn_c = 0.f;
    if (s == 0) {
        const float* lp = gsum + (size_t)b * G3;
        gr_c = lp[k]; gz_c = lp[HID + k]; gn_c = lp[2 * HID + k];
    }

    for (int i = 0; i < T1; i++) {
        float gr_n = 0.f, gz_n = 0.f, gn_n = 0.f;
        if (s == 0 && i + 1 < T1) {
            const float* lp = gsum + ((size_t)(i + 1) * BB + b) * G3;
            gr_n = lp[k]; gz_n = lp[HID + k]; gn_n = lp[2 * HID + k];
        }
        int ar = 0, az = 0, an = 0;
#pragma unroll
        for (int cc = 0; cc < 32; cc++) {
            int hv = hs8w[s * 32 + cc];   // 2 addresses per wave -> broadcast, free
            ar = dot4(wR[cc], hv, ar);
            az = dot4(wZ[cc], hv, az);
            an = dot4(wN[cc], hv, an);
        }
        ar += __shfl_xor(ar, 1); az += __shfl_xor(az, 1); an += __shfl_xor(an, 1);
        __syncthreads();   // all reads of hs8w done
        if (s == 0) {
            float arf = (float)ar * sR, azf = (float)az * sZ, anf = (float)an * sN;
            float r = 1.f / (1.f + expf(-(gr_c + arf + bhr)));
            float z = 1.f / (1.f + expf(-(gz_c + azf + bhz)));
            float n = tanhf(gn_c + r * (anf + bhn));
            float hold = hs32[k];
            float hnew = (1.f - z) * n + z * hold;
            hs32[k] = hnew;
            store[((size_t)b * T1 + i) * HID + k] = hnew;
            int q = max(-127, min(127, __float2int_rn(hnew * SCALE_H)));
            ((char*)hs8w)[k] = (char)q;
        }
        __syncthreads();   // writes visible for next step
        gr_c = gr_n; gz_c = gz_n; gn_c = gn_n;
    }
}

// ---------------- scores = U @ ws2^T ----------------
__global__ void k_scores(const float* __restrict__ U, const float* __restrict__ ws2, float* __restrict__ sbuf) {
    int flat = blockIdx.x * 256 + threadIdx.x;
    if (flat < BB * T1 * NHEADS) {
        int m = flat / NHEADS, h = flat % NHEADS;
        const float* u = U + (size_t)m * HID;
        const float* w = ws2 + h * HID;
        float acc = 0.f;
        for (int c = 0; c < HID; c += 4) {
            float4 u4 = *(const float4*)(u + c);
            float4 w4 = *(const float4*)(w + c);
            acc += u4.x * w4.x + u4.y * w4.y + u4.z * w4.z + u4.w * w4.w;
        }
        sbuf[flat] = acc;
    }
}

// ---------------- parallel per-(b,h) softmax: max-reduce + prefix scan ----------------
__global__ __launch_bounds__(128) void k_softmax_par(const float* __restrict__ sbuf,
                                                     float* __restrict__ ebuf, float* __restrict__ rD) {
    __shared__ float a[128];
    int bh = blockIdx.x;            // b*NHEADS + h
    int b = bh / NHEADS, h = bh % NHEADS;
    int t = threadIdx.x;
    const float* sp = sbuf + (size_t)b * T1 * NHEADS + h;
    float sv = (t < T1) ? sp[t * NHEADS] : -1e30f;
    a[t] = sv;
    __syncthreads();
#pragma unroll
    for (int off = 64; off >= 1; off >>= 1) {
        if (t < off) a[t] = fmaxf(a[t], a[t + off]);
        __syncthreads();
    }
    float m = a[0];
    __syncthreads();
    float e = (t < T1) ? expf(sv - m) : 0.f;
    a[t] = e;
#pragma unroll
    for (int off = 1; off < 128; off <<= 1) {
        __syncthreads();
        float v = (t >= off) ? a[t - off] : 0.f;
        __syncthreads();
        a[t] += v;
    }
    if (t < T1) {
        ebuf[(b * T1 + t) * NHEADS + h] = e;
        rD[(b * T1 + t) * NHEADS + h] = 1.f / a[t];
    }
}

// ---------------- alphas output ----------------
__global__ void k_alphas(const float* __restrict__ ebuf, const float* __restrict__ rD, float* __restrict__ alph) {
    int flat = blockIdx.x * 256 + threadIdx.x;
    const int TOT = T1 * BB * T1 * NHEADS;
    if (flat < TOT) {
        int i = flat / (BB * T1 * NHEADS);
        int rem = flat % (BB * T1 * NHEADS);
        int b = rem / (T1 * NHEADS);
        int rem2 = rem % (T1 * NHEADS);
        int t = rem2 / NHEADS, h = rem2 % NHEADS;
        float v = 0.f;
        if (t <= i) v = ebuf[(b * T1 + t) * NHEADS + h] * rD[(b * T1 + i) * NHEADS + h];
        alph[flat] = v;
    }
}

// ---------------- ctx prefix scan ----------------
__global__ __launch_bounds__(256) void k_ctx(const float* __restrict__ ebuf, const float* __restrict__ rD,
                                             const float* __restrict__ store, float* __restrict__ ctx) {
    __shared__ float eL[T1], rL[T1];
    int b = blockIdx.x / NHEADS, h = blockIdx.x % NHEADS;
    int k = threadIdx.x;
    if (k < T1) {
        eL[k] = ebuf[(b * T1 + k) * NHEADS + h];
        rL[k] = rD[(b * T1 + k) * NHEADS + h];
    }
    __syncthreads();
    float acc = 0.f;
#pragma unroll 4
    for (int t = 0; t < T1; t++) {
        acc += eL[t] * store[((size_t)b * T1 + t) * HID + k];
        ctx[((size_t)t * BB + b) * ATT + h * HID + k] = acc * rL[t];
    }
}

// ---------------- expert bucketing (R9-proven) ----------------
__global__ void k_count(const int* __restrict__ trace, int* __restrict__ cnt) {
    int idx = blockIdx.x * 256 + threadIdx.x;
    if (idx < T1 * BB) {
        int i = idx >> 6, b = idx & 63;
        int node = trace[b * TT + i + 1];
        atomicAdd(&cnt[node], 1);
    }
}

__global__ __launch_bounds__(256) void k_scan(const int* __restrict__ cnt, int* __restrict__ boff) {
    __shared__ int part[256];
    int t = threadIdx.x;
    int s0 = 0;
#pragma unroll
    for (int j = 0; j < 8; j++) { int idx = t * 8 + j; if (idx < NNODE + 1) s0 += cnt[idx]; }
    part[t] = s0;
    __syncthreads();
    for (int off = 1; off < 256; off <<= 1) {
        int u = (t >= off) ? part[t - off] : 0;
        __syncthreads();
        part[t] += u;
        __syncthreads();
    }
    int run = part[t] - s0;
    for (int j = 0; j < 8; j++) {
        int idx = t * 8 + j;
        if (idx < NNODE + 1) { boff[idx] = run; run += cnt[idx]; }
    }
    if (t == 255) boff[NNODE + 1] = part[255];
}

__global__ void k_scatter(const int* __restrict__ trace, const int* __restrict__ boff,
                          int* __restrict__ cur, int* __restrict__ items) {
    int idx = blockIdx.x * 256 + threadIdx.x;
    if (idx < T1 * BB) {
        int i = idx >> 6, b = idx & 63;
        int node = trace[b * TT + i + 1];
        int pos = atomicAdd(&cur[node], 1);
        items[boff[node] + pos] = idx;
    }
}

// one block per expert: stream weights once for all its items (chunks of 8)
__global__ __launch_bounds__(256) void k_pred2(
    const float* __restrict__ ctx, const float* __restrict__ pw, const float* __restrict__ pb,
    const int* __restrict__ boff, const int* __restrict__ items, float* __restrict__ outs)
{
    __shared__ float cl[8][ATT];
    __shared__ float red[16][16][8];
    int e = blockIdx.x;
    int start = boff[e], end = boff[e + 1];
    if (start == end) return;
    int tid = threadIdx.x;
    int d = tid & 15, ks = tid >> 4;
    const float* w = pw + (size_t)e * ATT * DD;
    float biasv = pb[e * DD + d];
    for (int c0 = start; c0 < end; c0 += 8) {
        int cn = min(8, end - c0);
        for (int j = 0; j < cn; j++) {
            int item = items[c0 + j];
            const float* cp = ctx + (size_t)item * ATT;
            for (int x = tid; x < ATT; x += 256) cl[j][x] = cp[x];
        }
        __syncthreads();
        float acc[8];
#pragma unroll
        for (int j = 0; j < 8; j++) acc[j] = 0.f;
        for (int kx = ks * 80; kx < ks * 80 + 80; kx++) {
            float wv = w[kx * DD + d];
#pragma unroll
            for (int j = 0; j < 8; j++) acc[j] += cl[j][kx] * wv;
        }
#pragma unroll
        for (int j = 0; j < 8; j++) red[ks][d][j] = acc[j];
        __syncthreads();
#pragma unroll
        for (int st = 8; st >= 1; st >>= 1) {
            if (ks < st) {
#pragma unroll
                for (int j = 0; j < 8; j++) red[ks][d][j] += red[ks + st][d][j];
            }
            __syncthreads();
        }
        if (ks == 0) {
            for (int j = 0; j < cn; j++) {
                int item = items[c0 + j];
                outs[(size_t)item * DD + d] = red[0][d][j] + biasv;
            }
        }
        __syncthreads();
    }
}

extern "C" void kernel_launch(void* const* d_in, const int* in_sizes, int n_in,
                              void* d_out, int out_size, void* d_ws, size_t ws_size,
                              hipStream_t stream) {
    const float* program_emb = (const float*)d_in[0];
    const float* h0       = (const float*)d_in[1];
    const float* node_emb = (const float*)d_in[2];
    const float* label_emb= (const float*)d_in[3];
    const float* w_ih     = (const float*)d_in[4];
    const float* w_hh     = (const float*)d_in[5];
    const float* b_ih     = (const float*)d_in[6];
    const float* b_hh     = (const float*)d_in[7];
    const float* ws1      = (const float*)d_in[8];
    const float* ws2      = (const float*)d_in[9];
    const float* pred_w   = (const float*)d_in[10];
    const float* pred_b   = (const float*)d_in[11];
    const int*   trace    = (const int*)d_in[12];
    const int*   na       = (const int*)d_in[13];

    // ---- R9-proven layout (floats), UNCHANGED; whh8q/wsc occupy the old whh16 slot ----
    float*          ws      = (float*)d_ws;
    float*          store   = ws + 0;           // [0 .. 2,080,768)
    unsigned short* wihT16  = (unsigned short*)(ws + 2080768);   // dead after Ubuf mgemm
    unsigned short* ws1T16  = (unsigned short*)(ws + 2409472);   // dead after Ubuf mgemm
    float*          prog_t  = ws + 2803712;
    float*          node_t  = ws + 2852864;
    float*          sbuf    = ws + 4389632;
    float*          ebuf    = ws + 4430272;
    float*          rD      = ws + 4470912;
    float*          label_p = ws + 4511568;     // gsum in-place; dead after rec8
    float*          Ubuf    = ws + 10753872;    // dead after k_scores
    int*            whh8q   = (int*)(ws + 12834640);   // 768*64 ints = 49,152 (old whh16 slot; dead after rec8)
    float*          wsc     = ws + 12883792;           // 768 floats (dead after rec8)
    float*          ctx     = ws + 4511568;     // [.. 14,915,408) aliases label_p/Ubuf/whh8q/wsc
    int*            cnt     = (int*)(ws + 2080768);    // over dead wihT16
    int*            cur     = cnt + 2048;
    int*            boff    = cur + 2048;
    int*            items   = boff + 2048;

    float* outs = (float*)d_out;
    float* alph = outs + T1 * BB * DD;

    // P1: static precompute
    k_tcvt<<<2568, 256, 0, stream>>>(w_ih, wihT16, G3, 856);
    k_tcvt<<<256, 256, 0, stream>>>(ws1, ws1T16, HID, HID);
    k_quant<<<G3, 64, 0, stream>>>(w_hh, whh8q, wsc);
    k_mgemm<<<12,   256, 0, stream>>>(program_emb, wihT16, prog_t, b_ih,   nullptr, nullptr, 0, 64,   256, G3,  256, 12, 300, G3, 0);
    k_mgemm<<<384,  256, 0, stream>>>(node_emb,    wihT16, node_t, nullptr, nullptr, nullptr, 0, 2001, 300, G3,  300, 12, 556, G3, 0);
    k_mgemm<<<1524, 256, 0, stream>>>(label_emb,   wihT16, label_p, nullptr, trace,  na,      2, 8128, 300, G3,  300, 12, 0,   G3, 0);
    k_addgi<<<6096, 256, 0, stream>>>(label_p, node_t, prog_t, trace);

    // P2: sequential recurrence — int8 register-resident weights
    rec8_kernel<<<64, 512, 0, stream>>>(h0, whh8q, wsc, b_hh, label_p, store);

    // P3: parallel attention + prediction
    k_mgemm<<<508, 256, 0, stream>>>(store, ws1T16, Ubuf, nullptr, nullptr, nullptr, 0, 8128, 256, HID, 256, 4, 0, HID, 1);
    k_scores<<<159, 256, 0, stream>>>(Ubuf, ws2, sbuf);
    k_softmax_par<<<BB * NHEADS, 128, 0, stream>>>(sbuf, ebuf, rD);
    k_alphas<<<20162, 256, 0, stream>>>(ebuf, rD, alph);
    k_ctx<<<320, 256, 0, stream>>>(ebuf, rD, store, ctx);

    // expert-bucketed prediction (R9-proven)
    hipMemsetAsync(cnt, 0, 2 * 2048 * sizeof(int), stream);
    k_count<<<32, 256, 0, stream>>>(trace, cnt);
    k_scan<<<1, 256, 0, stream>>>(cnt, boff);
    k_scatter<<<32, 256, 0, stream>>>(trace, boff, cur, items);
    k_pred2<<<NNODE + 1, 256, 0, stream>>>(ctx, pred_w, pred_b, boff, items, outs);
}